// Round 1
// baseline (6868.428 us; speedup 1.0000x reference)
//
#include <hip/hip_runtime.h>
#include <cstdint>
#include <cstddef>

// LSTMClassifier: 36 independent 2-layer LSTMs (H=256,G=1024), B=32, T=128 + MLP head.
// Round 1 design: decoupled passes, one WG per stream for recurrences, bf16 MFMA
// (16x16x32) with fp32 accumulators and fp32 cell state. No inter-WG sync.
// ws usage ~134.5 MB: [Whh1|Wih2|Whh2 bf16][h1_all bf16][h2_final f32][partial f32]

constexpr int kN = 36, kH = 256, kG = 1024, kB = 32, kT = 128, kSpec = 6, kOut = 30;
constexpr int kHP = 264; // LDS row stride (bf16): 264*2=528 B, 16B-aligned rows, odd-ish bank pattern

typedef __bf16 bf16;
typedef __bf16 bf16x8 __attribute__((ext_vector_type(8)));
typedef __bf16 bf16x4 __attribute__((ext_vector_type(4)));
typedef float f32x4 __attribute__((ext_vector_type(4)));

__device__ __forceinline__ float sigm(float v) { return 1.f / (1.f + __expf(-v)); }
__device__ __forceinline__ float tanh_f(float v) {
  v = fminf(15.f, fmaxf(-15.f, v));
  float e = __expf(2.f * v);
  return (e - 1.f) / (e + 1.f);
}

// ---- convert the three big recurrent weight tensors fp32 -> bf16 ----
__global__ __launch_bounds__(256) void k_convert(
    const float* __restrict__ wa, const float* __restrict__ wb, const float* __restrict__ wc,
    bf16* __restrict__ oa, bf16* __restrict__ ob, bf16* __restrict__ oc)
{
  const size_t tot4 = (size_t)kN * kG * kH / 4;
  size_t i = (size_t)blockIdx.x * 256 + threadIdx.x;
  if (i >= tot4) return;
  const float4 va = ((const float4*)wa)[i];
  const float4 vb = ((const float4*)wb)[i];
  const float4 vc = ((const float4*)wc)[i];
  bf16x4 ra, rb, rc;
  ra[0] = (bf16)va.x; ra[1] = (bf16)va.y; ra[2] = (bf16)va.z; ra[3] = (bf16)va.w;
  rb[0] = (bf16)vb.x; rb[1] = (bf16)vb.y; rb[2] = (bf16)vb.z; rb[3] = (bf16)vb.w;
  rc[0] = (bf16)vc.x; rc[1] = (bf16)vc.y; rc[2] = (bf16)vc.z; rc[3] = (bf16)vc.w;
  ((bf16x4*)oa)[i] = ra;
  ((bf16x4*)ob)[i] = rb;
  ((bf16x4*)oc)[i] = rc;
}

// ---- layer-1 recurrence: one WG per stream, all 32 batches, full T loop ----
// Per step: gates[32,1024] = x_t (outer) + h1[32,256] @ Whh1^T, MFMA 16x16x32.
// Wave w owns gate columns [w*32, w*32+32) of each of the 4 gate blocks, i.e.
// N-tiles {2w,2w+1}+{0,16,32,48}; i/f/g/o for one h element share lane+reg.
__global__ __launch_bounds__(512, 2) void k_layer1(
    const float* __restrict__ x, const float* __restrict__ Wih1,
    const float* __restrict__ bih1, const float* __restrict__ bhh1,
    const bf16* __restrict__ Whh1bf, bf16* __restrict__ h1_all)
{
  const int n = blockIdx.x;
  const int tid = threadIdx.x;
  const int wv = tid >> 6;
  const int lane = tid & 63;
  const int l15 = lane & 15;
  const int l4 = lane >> 4;

  __shared__ bf16 hbf[kB][kHP];
  __shared__ float xsh[kT][kB];

  for (int i = tid; i < kB * kT; i += 512) {
    int b = i >> 7, t = i & (kT - 1);
    xsh[t][b] = x[((size_t)b * kT + t) * kN + n];
  }
  for (int i = tid; i < kB * kHP; i += 512) ((bf16*)hbf)[i] = (bf16)0.f;

  const bf16* __restrict__ wb = Whh1bf + (size_t)n * kG * kH;
  float wih_s[2][4], bg_s[2][4];
  int boff[2][4];
#pragma unroll
  for (int jj = 0; jj < 2; ++jj)
#pragma unroll
    for (int gt = 0; gt < 4; ++gt) {
      int gg = (2 * wv + jj) * 16 + l15 + 256 * gt;
      wih_s[jj][gt] = Wih1[n * kG + gg];
      bg_s[jj][gt] = bih1[n * kG + gg] + bhh1[n * kG + gg];
      boff[jj][gt] = gg * kH + l4 * 8;
    }

  float cst[2][2][4];
#pragma unroll
  for (int a = 0; a < 2; ++a)
#pragma unroll
    for (int j = 0; j < 2; ++j)
#pragma unroll
      for (int r = 0; r < 4; ++r) cst[a][j][r] = 0.f;

  __syncthreads();

#pragma unroll 1
  for (int t = 0; t < kT; ++t) {
    // A fragments: A[m=lane&15 (+16*mt)][k=(lane>>4)*8+j], k-step = 32
    bf16x8 A[2][8];
#pragma unroll
    for (int mt = 0; mt < 2; ++mt)
#pragma unroll
      for (int ks = 0; ks < 8; ++ks)
        A[mt][ks] = *(const bf16x8*)&hbf[mt * 16 + l15][ks * 32 + l4 * 8];
    __syncthreads(); // protect hbf: everyone finished reading before writers run

    // acc init: x_t * Wih1 + (bih1+bhh1), fp32 (no double-rounding of bias/input)
    f32x4 acc[2][2][4];
#pragma unroll
    for (int mt = 0; mt < 2; ++mt)
#pragma unroll
      for (int jj = 0; jj < 2; ++jj)
#pragma unroll
        for (int gt = 0; gt < 4; ++gt)
#pragma unroll
          for (int r = 0; r < 4; ++r)
            acc[mt][jj][gt][r] = xsh[t][mt * 16 + l4 * 4 + r] * wih_s[jj][gt] + bg_s[jj][gt];

    // MFMA: ks outer so the 16 accumulation chains interleave (no back-to-back dep)
#pragma unroll
    for (int ks = 0; ks < 8; ++ks)
#pragma unroll
      for (int jj = 0; jj < 2; ++jj)
#pragma unroll
        for (int gt = 0; gt < 4; ++gt) {
          bf16x8 Bf = *(const bf16x8*)(wb + boff[jj][gt] + ks * 32);
          acc[0][jj][gt] = __builtin_amdgcn_mfma_f32_16x16x32_bf16(A[0][ks], Bf, acc[0][jj][gt], 0, 0, 0);
          acc[1][jj][gt] = __builtin_amdgcn_mfma_f32_16x16x32_bf16(A[1][ks], Bf, acc[1][jj][gt], 0, 0, 0);
        }

    // cell update: i=block0, f=block1, g=block2, o=block3 (torch order)
#pragma unroll
    for (int mt = 0; mt < 2; ++mt)
#pragma unroll
      for (int jj = 0; jj < 2; ++jj) {
        const int kcol = (2 * wv + jj) * 16 + l15;
#pragma unroll
        for (int r = 0; r < 4; ++r) {
          float cc = sigm(acc[mt][jj][1][r]) * cst[mt][jj][r]
                   + sigm(acc[mt][jj][0][r]) * tanh_f(acc[mt][jj][2][r]);
          cst[mt][jj][r] = cc;
          float hv = sigm(acc[mt][jj][3][r]) * tanh_f(cc);
          hbf[mt * 16 + l4 * 4 + r][kcol] = (bf16)hv;
        }
      }
    __syncthreads(); // h writes visible

    // coalesced copy-out h1(t) -> global [n][t][b][h]
    {
      const int m = tid >> 4;
      const int off = (tid & 15) * 16;
      bf16x8 v0 = *(const bf16x8*)&hbf[m][off];
      bf16x8 v1 = *(const bf16x8*)&hbf[m][off + 8];
      bf16x8* dst = (bf16x8*)(h1_all + (((size_t)n * kT + t) * kB + m) * kH + off);
      dst[0] = v0;
      dst[1] = v1;
    }
  }
}

// ---- layer-2 recurrence: gates = h1(t)@Wih2^T + h2(t-1)@Whh2^T + bg2 ----
__global__ __launch_bounds__(512, 2) void k_layer2(
    const float* __restrict__ bih2, const float* __restrict__ bhh2,
    const bf16* __restrict__ W2ibf, const bf16* __restrict__ W2hbf,
    const bf16* __restrict__ h1_all, float* __restrict__ h2_final)
{
  const int n = blockIdx.x;
  const int tid = threadIdx.x;
  const int wv = tid >> 6;
  const int lane = tid & 63;
  const int l15 = lane & 15;
  const int l4 = lane >> 4;

  __shared__ bf16 hbf[kB][kHP];
  for (int i = tid; i < kB * kHP; i += 512) ((bf16*)hbf)[i] = (bf16)0.f;

  const bf16* __restrict__ wbi = W2ibf + (size_t)n * kG * kH;
  const bf16* __restrict__ wbh = W2hbf + (size_t)n * kG * kH;
  float bg_s[2][4];
  int boff[2][4];
#pragma unroll
  for (int jj = 0; jj < 2; ++jj)
#pragma unroll
    for (int gt = 0; gt < 4; ++gt) {
      int gg = (2 * wv + jj) * 16 + l15 + 256 * gt;
      bg_s[jj][gt] = bih2[n * kG + gg] + bhh2[n * kG + gg];
      boff[jj][gt] = gg * kH + l4 * 8;
    }

  float cst[2][2][4];
#pragma unroll
  for (int a = 0; a < 2; ++a)
#pragma unroll
    for (int j = 0; j < 2; ++j)
#pragma unroll
      for (int r = 0; r < 4; ++r) cst[a][j][r] = 0.f;

  __syncthreads();

#pragma unroll 1
  for (int t = 0; t < kT; ++t) {
    const bf16* __restrict__ hp = h1_all + ((size_t)n * kT + t) * kB * kH;
    bf16x8 A[2][8];
#pragma unroll
    for (int mt = 0; mt < 2; ++mt)
#pragma unroll
      for (int ks = 0; ks < 8; ++ks)
        A[mt][ks] = *(const bf16x8*)(hp + (mt * 16 + l15) * kH + ks * 32 + l4 * 8);

    f32x4 acc[2][2][4];
#pragma unroll
    for (int mt = 0; mt < 2; ++mt)
#pragma unroll
      for (int jj = 0; jj < 2; ++jj)
#pragma unroll
        for (int gt = 0; gt < 4; ++gt)
#pragma unroll
          for (int r = 0; r < 4; ++r) acc[mt][jj][gt][r] = bg_s[jj][gt];

    // pass 1: input-side GEMM with A = h1(t)
#pragma unroll
    for (int ks = 0; ks < 8; ++ks)
#pragma unroll
      for (int jj = 0; jj < 2; ++jj)
#pragma unroll
        for (int gt = 0; gt < 4; ++gt) {
          bf16x8 Bf = *(const bf16x8*)(wbi + boff[jj][gt] + ks * 32);
          acc[0][jj][gt] = __builtin_amdgcn_mfma_f32_16x16x32_bf16(A[0][ks], Bf, acc[0][jj][gt], 0, 0, 0);
          acc[1][jj][gt] = __builtin_amdgcn_mfma_f32_16x16x32_bf16(A[1][ks], Bf, acc[1][jj][gt], 0, 0, 0);
        }

    // pass 2: recurrent GEMM with A = h2(t-1) from LDS
#pragma unroll
    for (int mt = 0; mt < 2; ++mt)
#pragma unroll
      for (int ks = 0; ks < 8; ++ks)
        A[mt][ks] = *(const bf16x8*)&hbf[mt * 16 + l15][ks * 32 + l4 * 8];
    __syncthreads(); // reads of h2(t-1) done before writers below

#pragma unroll
    for (int ks = 0; ks < 8; ++ks)
#pragma unroll
      for (int jj = 0; jj < 2; ++jj)
#pragma unroll
        for (int gt = 0; gt < 4; ++gt) {
          bf16x8 Bf = *(const bf16x8*)(wbh + boff[jj][gt] + ks * 32);
          acc[0][jj][gt] = __builtin_amdgcn_mfma_f32_16x16x32_bf16(A[0][ks], Bf, acc[0][jj][gt], 0, 0, 0);
          acc[1][jj][gt] = __builtin_amdgcn_mfma_f32_16x16x32_bf16(A[1][ks], Bf, acc[1][jj][gt], 0, 0, 0);
        }

#pragma unroll
    for (int mt = 0; mt < 2; ++mt)
#pragma unroll
      for (int jj = 0; jj < 2; ++jj) {
        const int kcol = (2 * wv + jj) * 16 + l15;
#pragma unroll
        for (int r = 0; r < 4; ++r) {
          float cc = sigm(acc[mt][jj][1][r]) * cst[mt][jj][r]
                   + sigm(acc[mt][jj][0][r]) * tanh_f(acc[mt][jj][2][r]);
          cst[mt][jj][r] = cc;
          float hv = sigm(acc[mt][jj][3][r]) * tanh_f(cc);
          const int m = mt * 16 + l4 * 4 + r;
          hbf[m][kcol] = (bf16)hv;
          if (t == kT - 1) h2_final[((size_t)n * kB + m) * kH + kcol] = hv; // fp32 features
        }
      }
    __syncthreads();
  }
}

// ---- head: feat = [h2 per stream (36x256) | spec@Wspec+bspec (256)] -> Wp1/ReLU/Wp2 ----
__global__ __launch_bounds__(256) void k_head1(
    const float* __restrict__ spec, const float* __restrict__ Wspec,
    const float* __restrict__ bspec, const float* __restrict__ Wp1,
    const float* __restrict__ h2f, float* __restrict__ partial)
{
  const int kc = blockIdx.x; // 0..36 feature chunk
  const int b = blockIdx.y;  // 0..31
  const int o = threadIdx.x; // 0..255
  __shared__ float fs[kH];
  if (kc < kN) {
    fs[o] = h2f[((size_t)kc * kB + b) * kH + o];
  } else {
    float v = bspec[o];
#pragma unroll
    for (int s = 0; s < kSpec; ++s) v += spec[b * kSpec + s] * Wspec[s * kH + o];
    fs[o] = v;
  }
  __syncthreads();
  const float* __restrict__ wp = Wp1 + (size_t)kc * 256 * kH + o;
  float a = 0.f;
#pragma unroll 8
  for (int i = 0; i < 256; ++i) a += fs[i] * wp[(size_t)i * kH];
  partial[((size_t)kc * kB + b) * kH + o] = a;
}

__global__ __launch_bounds__(256) void k_head2(
    const float* __restrict__ bp1, const float* __restrict__ Wp2,
    const float* __restrict__ bp2, const float* __restrict__ partial,
    float* __restrict__ out)
{
  const int b = blockIdx.x;
  const int o = threadIdx.x;
  __shared__ float hid[kH];
  float a = bp1[o];
#pragma unroll
  for (int kc = 0; kc < kN + 1; ++kc) a += partial[((size_t)kc * kB + b) * kH + o];
  hid[o] = fmaxf(a, 0.f);
  __syncthreads();
  if (o < kOut) {
    float r = bp2[o];
#pragma unroll 8
    for (int h = 0; h < kH; ++h) r += hid[h] * Wp2[h * kOut + o];
    out[b * kOut + o] = r;
  }
}

extern "C" void kernel_launch(void* const* d_in, const int* in_sizes, int n_in,
                              void* d_out, int out_size, void* d_ws, size_t ws_size,
                              hipStream_t stream) {
  const float* x = (const float*)d_in[0];
  const float* spec = (const float*)d_in[1];
  const float* Wih1 = (const float*)d_in[2];
  const float* Whh1 = (const float*)d_in[3];
  const float* bih1 = (const float*)d_in[4];
  const float* bhh1 = (const float*)d_in[5];
  const float* Wih2 = (const float*)d_in[6];
  const float* Whh2 = (const float*)d_in[7];
  const float* bih2 = (const float*)d_in[8];
  const float* bhh2 = (const float*)d_in[9];
  const float* Wspec = (const float*)d_in[10];
  const float* bspec = (const float*)d_in[11];
  const float* Wp1 = (const float*)d_in[12];
  const float* bp1 = (const float*)d_in[13];
  const float* Wp2 = (const float*)d_in[14];
  const float* bp2 = (const float*)d_in[15];
  float* out = (float*)d_out;

  // ws layout (bytes): needs ~134.5 MB total
  const size_t WSZ = (size_t)kN * kG * kH; // elems per weight tensor
  bf16* Wbf1 = (bf16*)d_ws;
  bf16* Wbf2i = Wbf1 + WSZ;
  bf16* Wbf2h = Wbf2i + WSZ;
  bf16* h1_all = Wbf2h + WSZ;                                  // [N][T][B][H] bf16
  float* h2_final = (float*)(h1_all + (size_t)kN * kT * kB * kH); // [N][B][H] f32
  float* partial = h2_final + (size_t)kN * kB * kH;            // [37][B][H] f32

  const int cvt_blocks = (int)((WSZ / 4 + 255) / 256); // 9216
  k_convert<<<dim3(cvt_blocks), dim3(256), 0, stream>>>(Whh1, Wih2, Whh2, Wbf1, Wbf2i, Wbf2h);
  k_layer1<<<dim3(kN), dim3(512), 0, stream>>>(x, Wih1, bih1, bhh1, Wbf1, h1_all);
  k_layer2<<<dim3(kN), dim3(512), 0, stream>>>(bih2, bhh2, Wbf2i, Wbf2h, h1_all, h2_final);
  k_head1<<<dim3(kN + 1, kB), dim3(256), 0, stream>>>(spec, Wspec, bspec, Wp1, h2_final, partial);
  k_head2<<<dim3(kB), dim3(256), 0, stream>>>(bp1, Wp2, bp2, partial, out);
}